// Round 1
// baseline (823.993 us; speedup 1.0000x reference)
//
#include <hip/hip_runtime.h>
#include <hip/hip_bf16.h>

// Problem: B=16, S=257, H=768, V=30522, P=32, topk=8 (fixed shapes).
#define BB 16
#define SS 257
#define SP 256      // S-1
#define HH 768
#define VV 30522
#define NF2 15261   // VV/2 (row is exactly NF2 float2's; row byte offset % 8 == 0)
#define PP 32
#define KK 8
#define CAP 2048    // candidate buffer; also holds 256*8 fallback entries

// ---------------------------------------------------------------------------
// Pass A (row-wise): per (b,s) row of 30522 logits compute
//   Z = sum(exp(x))  -> invZ workspace      (softmax denom; no max-shift needed,
//                                            inputs are N(0,1) so exp() is safe)
//   top-8 of mask*log1p(relu(x))  -> expert_weights/expert_ids
//   scatter rm_seq atomics, write mask output.
// Top-8 trick: log1p(relu(.)) is monotone, so select on raw values; candidates
// above T=3.0 (~41 expected of 30522) go to an LDS list; exact fallback
// (per-thread insertion sort) if <8 or overflow. Tie-break = jax top_k:
// value desc, index asc.
// ---------------------------------------------------------------------------
__global__ __launch_bounds__(256) void rowstats_kernel(
    const float* __restrict__ logits, const float* __restrict__ amask,
    float* __restrict__ invZ, float* __restrict__ o_rm,
    float* __restrict__ o_mask, float* __restrict__ o_ids,
    float* __restrict__ o_w)
{
  const int tid = threadIdx.x;
  const int row = blockIdx.x;          // 0..4095
  const int b = row >> 8, s = row & 255;
  const float* lp = logits + (size_t)(b * SS + s + 1) * VV;
  const float mval = amask[b * SS + s + 1];
  const bool mz = (mval != 0.0f);

  __shared__ float cv[CAP];
  __shared__ int   ci[CAP];
  __shared__ float red[256];
  __shared__ float bv[256];
  __shared__ int   bi[256];
  __shared__ int   bs[256];
  __shared__ float selv[KK];
  __shared__ int   seli[KK];
  __shared__ int   cnt;
  if (tid == 0) cnt = 0;
  __syncthreads();

  const float2* lp2 = (const float2*)lp;
  float zsum = 0.0f;
  const float T = 3.0f;
  for (int c = tid; c < NF2; c += 256) {
    float2 x = lp2[c];
    zsum += __expf(x.x) + __expf(x.y);
    if (mz) {
      if (x.x > T) { int p = atomicAdd(&cnt, 1); if (p < CAP) { cv[p] = x.x; ci[p] = 2 * c; } }
      if (x.y > T) { int p = atomicAdd(&cnt, 1); if (p < CAP) { cv[p] = x.y; ci[p] = 2 * c + 1; } }
    }
  }
  red[tid] = zsum;
  __syncthreads();                       // also makes all candidate appends visible
  #pragma unroll
  for (int st = 128; st > 0; st >>= 1) {
    if (tid < st) red[tid] += red[tid + st];
    __syncthreads();
  }
  if (tid == 0) invZ[row] = 1.0f / red[0];

  int n = cnt;                           // block-uniform
  if (n < KK || n > CAP) {
    // Exact fallback: per-thread sorted top-8 over clamped masked values.
    float lv[KK]; int li[KK];
    #pragma unroll
    for (int j = 0; j < KK; ++j) { lv[j] = -1.0f; li[j] = 0; }
    for (int c = tid; c < NF2; c += 256) {
      float2 x = lp2[c];
      float v0 = mz ? fmaxf(x.x, 0.0f) : 0.0f;
      float v1 = mz ? fmaxf(x.y, 0.0f) : 0.0f;
      if (v0 > lv[KK - 1]) {             // strict >: equal value keeps earlier index
        #pragma unroll
        for (int j = KK - 1; j >= 1; --j) {
          bool a = lv[j - 1] < v0;
          bool q = lv[j] < v0;
          lv[j] = a ? lv[j - 1] : (q ? v0 : lv[j]);
          li[j] = a ? li[j - 1] : (q ? (2 * c) : li[j]);
        }
        if (lv[0] < v0) { lv[0] = v0; li[0] = 2 * c; }
      }
      if (v1 > lv[KK - 1]) {
        #pragma unroll
        for (int j = KK - 1; j >= 1; --j) {
          bool a = lv[j - 1] < v1;
          bool q = lv[j] < v1;
          lv[j] = a ? lv[j - 1] : (q ? v1 : lv[j]);
          li[j] = a ? li[j - 1] : (q ? (2 * c + 1) : li[j]);
        }
        if (lv[0] < v1) { lv[0] = v1; li[0] = 2 * c + 1; }
      }
    }
    __syncthreads();                     // done reading cv from append phase
    #pragma unroll
    for (int j = 0; j < KK; ++j) { cv[tid * KK + j] = lv[j]; ci[tid * KK + j] = li[j]; }
    n = CAP;
    __syncthreads();
  }

  // Extract top-8 from cv[0..n) with (value desc, index asc) order.
  #pragma unroll 1
  for (int k = 0; k < KK; ++k) {
    float mv = -3.402823466e38f; int mi = 0x7fffffff; int ms = -1;
    for (int j = tid; j < n; j += 256) {
      float v = cv[j]; int i = ci[j];
      if (v > mv || (v == mv && i < mi)) { mv = v; mi = i; ms = j; }
    }
    bv[tid] = mv; bi[tid] = mi; bs[tid] = ms;
    __syncthreads();
    #pragma unroll
    for (int st = 128; st > 0; st >>= 1) {
      if (tid < st) {
        float v2 = bv[tid + st]; int i2 = bi[tid + st];
        if (v2 > bv[tid] || (v2 == bv[tid] && i2 < bi[tid])) {
          bv[tid] = v2; bi[tid] = i2; bs[tid] = bs[tid + st];
        }
      }
      __syncthreads();
    }
    if (tid == 0) { selv[k] = bv[0]; seli[k] = bi[0]; cv[bs[0]] = -3.402823466e38f; }
    __syncthreads();
  }

  if (tid < KK) {
    float v = selv[tid];                 // >= 0 in both paths
    int id = seli[tid];
    float w = mval * log1pf(v);
    o_w[(size_t)row * KK + tid] = w;
    o_ids[(size_t)row * KK + tid] = (float)id;
    if (w > 0.0f) atomicAdd(&o_rm[(size_t)b * VV + id], 1.0f);
  }
  if (tid == 0) o_mask[row] = mval;
}

// ---------------------------------------------------------------------------
// Pass B (column-wise): per (b, v) accumulate over s:
//   router_softmax_sum[b,v] = sum_s exp(x)*invZ[b,s]
//   router_repr[b,v]        = log1p(max_s (mask? relu(x):0))   (monotone fold)
// ---------------------------------------------------------------------------
__global__ __launch_bounds__(256) void colstats_kernel(
    const float* __restrict__ logits, const float* __restrict__ amask,
    const float* __restrict__ invZ,
    float* __restrict__ o_rss, float* __restrict__ o_rrepr)
{
  const int b = blockIdx.y;
  const int c = blockIdx.x * 256 + threadIdx.x;   // float2 column index
  __shared__ float zi[SP];
  __shared__ float mm[SP];
  zi[threadIdx.x] = invZ[b * SP + threadIdx.x];
  mm[threadIdx.x] = amask[b * SS + 1 + threadIdx.x];
  __syncthreads();
  if (c >= NF2) return;
  const float2* base = (const float2*)(logits + (size_t)(b * SS + 1) * VV) + c;
  float a0 = 0.0f, a1 = 0.0f, c0 = 0.0f, c1 = 0.0f;
  #pragma unroll 4
  for (int s = 0; s < SP; ++s) {
    float2 x = base[(size_t)s * NF2];
    float iz = zi[s];
    a0 = fmaf(__expf(x.x), iz, a0);
    a1 = fmaf(__expf(x.y), iz, a1);
    if (mm[s] != 0.0f) { c0 = fmaxf(c0, x.x); c1 = fmaxf(c1, x.y); }
  }
  size_t o = (size_t)b * VV + 2 * (size_t)c;
  *(float2*)(o_rss + o)   = make_float2(a0, a1);
  *(float2*)(o_rrepr + o) = make_float2(log1pf(c0), log1pf(c1));
}

// ---------------------------------------------------------------------------
// W_tok (P,H) -> Wt (H,P) so the expert GEMM reads W coalesced.
// ---------------------------------------------------------------------------
__global__ __launch_bounds__(256) void transw_kernel(
    const float* __restrict__ W, float* __restrict__ Wt)
{
  int i = blockIdx.x * 256 + threadIdx.x;
  if (i < PP * HH) {
    int p = i / HH, k = i % HH;
    Wt[k * PP + p] = W[i];
  }
}

// ---------------------------------------------------------------------------
// expert_repr[b,s,p] = (hiddens[b,s,:] . W_tok[p,:] + b_tok[p]) * mask[b,s]
// One block per (b,s) row; hidden row staged in LDS; Wt reads coalesced.
// ---------------------------------------------------------------------------
__global__ __launch_bounds__(256) void expertk_kernel(
    const float* __restrict__ hs, const float* __restrict__ amask,
    const float* __restrict__ Wt, const float* __restrict__ btok,
    float* __restrict__ o_er)
{
  const int row = blockIdx.x;
  const int b = row >> 8, s = row & 255;
  const float* hp = hs + (size_t)(b * SS + s + 1) * HH;
  __shared__ float h[HH];
  __shared__ float psum[8][PP];
  for (int i = threadIdx.x; i < HH; i += 256) h[i] = hp[i];
  __syncthreads();
  const int p = threadIdx.x & 31, g = threadIdx.x >> 5;
  float acc = 0.0f;
  #pragma unroll 8
  for (int k = g * 96; k < g * 96 + 96; ++k) acc = fmaf(h[k], Wt[k * PP + p], acc);
  psum[g][p] = acc;
  __syncthreads();
  if (threadIdx.x < PP) {
    float r = 0.0f;
    #pragma unroll
    for (int g2 = 0; g2 < 8; ++g2) r += psum[g2][threadIdx.x];
    float mval = amask[b * SS + s + 1];
    o_er[(size_t)row * PP + threadIdx.x] = (r + btok[threadIdx.x]) * mval;
  }
}

// ---------------------------------------------------------------------------
// avg_cond = sum(rm_seq)/B ; avg_marg = sum_v max_b rm_seq[b,v]
// ---------------------------------------------------------------------------
__global__ __launch_bounds__(256) void reducerm_kernel(
    const float* __restrict__ rm, float* __restrict__ out01)
{
  int v = blockIdx.x * 256 + threadIdx.x;
  float sm = 0.0f, mx = 0.0f;
  if (v < VV) {
    #pragma unroll
    for (int b = 0; b < BB; ++b) {
      float r = rm[(size_t)b * VV + v];
      sm += r; mx = fmaxf(mx, r);
    }
  }
  __shared__ float rs[256], rx[256];
  rs[threadIdx.x] = sm; rx[threadIdx.x] = mx;
  __syncthreads();
  #pragma unroll
  for (int st = 128; st > 0; st >>= 1) {
    if (threadIdx.x < st) {
      rs[threadIdx.x] += rs[threadIdx.x + st];
      rx[threadIdx.x] += rx[threadIdx.x + st];
    }
    __syncthreads();
  }
  if (threadIdx.x == 0) {
    atomicAdd(&out01[0], rs[0] * (1.0f / BB));
    atomicAdd(&out01[1], rx[0]);
  }
}

extern "C" void kernel_launch(void* const* d_in, const int* in_sizes, int n_in,
                              void* d_out, int out_size, void* d_ws, size_t ws_size,
                              hipStream_t stream) {
  const float* hs     = (const float*)d_in[0];  // (16,257,768)
  const float* logits = (const float*)d_in[1];  // (16,257,30522)
  const float* amask  = (const float*)d_in[2];  // (16,257)
  const float* W      = (const float*)d_in[3];  // (32,768)
  const float* btok   = (const float*)d_in[4];  // (32,)
  // d_in[5] = topk scalar (8), compile-time constant here.

  float* out    = (float*)d_out;
  float* o_cond = out;                                  // [0]   (1,1)+(1,1)
  float* o_rm   = out + 2;                              // (16,30522)
  float* o_rss  = o_rm + (size_t)BB * VV;               // (16,30522)
  float* o_mask = o_rss + (size_t)BB * VV;              // (16,256)
  float* o_rrepr= o_mask + (size_t)BB * SP;             // (16,30522)
  float* o_ids  = o_rrepr + (size_t)BB * VV;            // (16,256,8) as float
  float* o_er   = o_ids + (size_t)BB * SP * KK;         // (16,256,32)
  float* o_w    = o_er + (size_t)BB * SP * PP;          // (16,256,8)

  float* wsf  = (float*)d_ws;
  float* invZ = wsf;            // 4096 floats
  float* Wt   = wsf + 4096;     // 24576 floats

  // zero avg_cond, avg_marg, rm_seq (contiguous prefix); ws/out are poisoned each call
  hipMemsetAsync(out, 0, (2 + (size_t)BB * VV) * sizeof(float), stream);

  rowstats_kernel<<<BB * SP, 256, 0, stream>>>(logits, amask, invZ, o_rm, o_mask, o_ids, o_w);
  colstats_kernel<<<dim3((NF2 + 255) / 256, BB), 256, 0, stream>>>(logits, amask, invZ, o_rss, o_rrepr);
  transw_kernel<<<(PP * HH + 255) / 256, 256, 0, stream>>>(W, Wt);
  expertk_kernel<<<BB * SP, 256, 0, stream>>>(hs, amask, Wt, btok, o_er);
  reducerm_kernel<<<(VV + 255) / 256, 256, 0, stream>>>(o_rm, o_cond);
}

// Round 2
// 787.196 us; speedup vs baseline: 1.0467x; 1.0467x over previous
//
#include <hip/hip_runtime.h>
#include <hip/hip_bf16.h>
#include <float.h>

// Problem: B=16, S=257, H=768, V=30522, P=32, topk=8 (fixed shapes).
#define BB 16
#define SS 257
#define SP 256      // S-1
#define HH 768
#define VV 30522
#define NF2 15261   // VV/2 (row is exactly NF2 float2's; row byte offset % 8 == 0)
#define PP 32
#define KK 8
#define CAP 2048    // candidate buffer; also holds 256*8 fallback entries

// ---------------------------------------------------------------------------
// Pass A (row-wise): per (b,s) row of 30522 logits compute
//   Z = sum(exp(x)) -> invZ ws   (no max-shift: inputs N(0,1), exp() safe)
//   top-8 of mask*log1p(relu(x)) -> expert_weights/ids (+ rm_seq scatter)
// log1p(relu(.)) is monotone => select on raw values; candidates above T=3.0
// (~41 of 30522 expected) appended to LDS; exact per-thread insertion-sort
// fallback if <8 or overflow. Tie-break = jax top_k (value desc, index asc).
// v2: 4-wide load batching for MLP; wave-shuffle Z-reduce; barrier-free
// single-wave shuffle-argmax extraction (was ~72 barriers/block).
// ---------------------------------------------------------------------------
__global__ __launch_bounds__(256) void rowstats_kernel(
    const float* __restrict__ logits, const float* __restrict__ amask,
    float* __restrict__ invZ, float* __restrict__ o_rm,
    float* __restrict__ o_mask, float* __restrict__ o_ids,
    float* __restrict__ o_w)
{
  const int tid = threadIdx.x;
  const int row = blockIdx.x;          // 0..4095
  const int b = row >> 8, s = row & 255;
  const float* lp = logits + (size_t)(b * SS + s + 1) * VV;
  const float mval = amask[b * SS + s + 1];
  const bool mz = (mval != 0.0f);

  __shared__ float cv[CAP];
  __shared__ int   ci[CAP];
  __shared__ float red[4];
  __shared__ int   cnt;
  if (tid == 0) cnt = 0;
  __syncthreads();

  const float2* lp2 = (const float2*)lp;
  const float T = 3.0f;
  float z0 = 0.0f, z1 = 0.0f, z2 = 0.0f, z3 = 0.0f;
  // 15261 = 256*59 + 157: 56 full strides in quads, then 4 guarded strides.
  for (int k = 0; k < 56; k += 4) {
    float2 x0 = lp2[tid + 256 * (k + 0)];
    float2 x1 = lp2[tid + 256 * (k + 1)];
    float2 x2 = lp2[tid + 256 * (k + 2)];
    float2 x3 = lp2[tid + 256 * (k + 3)];
    z0 += __expf(x0.x) + __expf(x0.y);
    z1 += __expf(x1.x) + __expf(x1.y);
    z2 += __expf(x2.x) + __expf(x2.y);
    z3 += __expf(x3.x) + __expf(x3.y);
    if (mz) {
      if (x0.x > T) { int p = atomicAdd(&cnt, 1); if (p < CAP) { cv[p] = x0.x; ci[p] = 2 * (tid + 256 * (k + 0)); } }
      if (x0.y > T) { int p = atomicAdd(&cnt, 1); if (p < CAP) { cv[p] = x0.y; ci[p] = 2 * (tid + 256 * (k + 0)) + 1; } }
      if (x1.x > T) { int p = atomicAdd(&cnt, 1); if (p < CAP) { cv[p] = x1.x; ci[p] = 2 * (tid + 256 * (k + 1)); } }
      if (x1.y > T) { int p = atomicAdd(&cnt, 1); if (p < CAP) { cv[p] = x1.y; ci[p] = 2 * (tid + 256 * (k + 1)) + 1; } }
      if (x2.x > T) { int p = atomicAdd(&cnt, 1); if (p < CAP) { cv[p] = x2.x; ci[p] = 2 * (tid + 256 * (k + 2)); } }
      if (x2.y > T) { int p = atomicAdd(&cnt, 1); if (p < CAP) { cv[p] = x2.y; ci[p] = 2 * (tid + 256 * (k + 2)) + 1; } }
      if (x3.x > T) { int p = atomicAdd(&cnt, 1); if (p < CAP) { cv[p] = x3.x; ci[p] = 2 * (tid + 256 * (k + 3)); } }
      if (x3.y > T) { int p = atomicAdd(&cnt, 1); if (p < CAP) { cv[p] = x3.y; ci[p] = 2 * (tid + 256 * (k + 3)) + 1; } }
    }
  }
  for (int k = 56; k < 60; ++k) {
    int c = tid + 256 * k;
    if (c < NF2) {
      float2 x = lp2[c];
      z0 += __expf(x.x) + __expf(x.y);
      if (mz) {
        if (x.x > T) { int p = atomicAdd(&cnt, 1); if (p < CAP) { cv[p] = x.x; ci[p] = 2 * c; } }
        if (x.y > T) { int p = atomicAdd(&cnt, 1); if (p < CAP) { cv[p] = x.y; ci[p] = 2 * c + 1; } }
      }
    }
  }
  float zsum = (z0 + z1) + (z2 + z3);
  #pragma unroll
  for (int off = 32; off; off >>= 1) zsum += __shfl_xor(zsum, off, 64);
  if ((tid & 63) == 0) red[tid >> 6] = zsum;
  __syncthreads();                       // also makes candidate appends visible
  if (tid == 0) invZ[row] = 1.0f / ((red[0] + red[1]) + (red[2] + red[3]));

  int n = cnt;                           // block-uniform after barrier
  if (n < KK || n > CAP) {
    // Exact fallback: per-thread sorted top-8 over clamped masked values.
    float lv[KK]; int li[KK];
    #pragma unroll
    for (int j = 0; j < KK; ++j) { lv[j] = -1.0f; li[j] = 0; }
    for (int c = tid; c < NF2; c += 256) {
      float2 x = lp2[c];
      float v0 = mz ? fmaxf(x.x, 0.0f) : 0.0f;
      float v1 = mz ? fmaxf(x.y, 0.0f) : 0.0f;
      if (v0 > lv[KK - 1]) {             // strict >: equal value keeps earlier index
        #pragma unroll
        for (int j = KK - 1; j >= 1; --j) {
          bool a = lv[j - 1] < v0;
          bool q = lv[j] < v0;
          lv[j] = a ? lv[j - 1] : (q ? v0 : lv[j]);
          li[j] = a ? li[j - 1] : (q ? (2 * c) : li[j]);
        }
        if (lv[0] < v0) { lv[0] = v0; li[0] = 2 * c; }
      }
      if (v1 > lv[KK - 1]) {
        #pragma unroll
        for (int j = KK - 1; j >= 1; --j) {
          bool a = lv[j - 1] < v1;
          bool q = lv[j] < v1;
          lv[j] = a ? lv[j - 1] : (q ? v1 : lv[j]);
          li[j] = a ? li[j - 1] : (q ? (2 * c + 1) : li[j]);
        }
        if (lv[0] < v1) { lv[0] = v1; li[0] = 2 * c + 1; }
      }
    }
    #pragma unroll
    for (int j = 0; j < KK; ++j) { cv[tid * KK + j] = lv[j]; ci[tid * KK + j] = li[j]; }
    n = CAP;
    __syncthreads();
  }

  // Barrier-free extraction: wave 0 only, shuffle-butterfly argmax × 8.
  if (tid < 64) {
    #pragma unroll 1
    for (int kk = 0; kk < KK; ++kk) {
      float mv = -FLT_MAX; int mi = 0x7fffffff; int ms = -1;
      for (int j = tid; j < n; j += 64) {
        float v = cv[j]; int ix = ci[j];
        if (v > mv || (v == mv && ix < mi)) { mv = v; mi = ix; ms = j; }
      }
      #pragma unroll
      for (int off = 32; off; off >>= 1) {
        float ov = __shfl_xor(mv, off, 64);
        int   oi = __shfl_xor(mi, off, 64);
        int   os = __shfl_xor(ms, off, 64);
        if (ov > mv || (ov == mv && oi < mi)) { mv = ov; mi = oi; ms = os; }
      }
      if (tid == 0) cv[ms] = -FLT_MAX;   // same-wave LDS: in-order, no barrier
      if (tid == kk) {
        float w = mval * log1pf(fmaxf(mv, 0.0f));
        o_w[(size_t)row * KK + kk] = w;
        o_ids[(size_t)row * KK + kk] = (float)mi;
        if (w > 0.0f) atomicAdd(&o_rm[(size_t)b * VV + mi], 1.0f);
      }
    }
  }
  if (tid == 0) o_mask[row] = mval;
}

// ---------------------------------------------------------------------------
// Pass B (column-wise): per (b, v) over s:
//   router_softmax_sum[b,v] = sum_s exp(x)*invZ[b,s]
//   router_repr[b,v]        = log1p(max_s (mask? relu(x):0))   (monotone fold)
// v2: 4 independent s-streams per thread (s, s+64, s+128, s+192) + unroll 2
// for 8 loads in flight; 8 independent accumulator chains.
// ---------------------------------------------------------------------------
__global__ __launch_bounds__(256) void colstats_kernel(
    const float* __restrict__ logits, const float* __restrict__ amask,
    const float* __restrict__ invZ,
    float* __restrict__ o_rss, float* __restrict__ o_rrepr)
{
  const int b = blockIdx.y;
  const int tid = threadIdx.x;
  const int c = blockIdx.x * 256 + tid;   // float2 column index
  __shared__ float zi[SP];
  __shared__ float mm[SP];
  zi[tid] = invZ[b * SP + tid];
  mm[tid] = amask[b * SS + 1 + tid];
  __syncthreads();
  if (c >= NF2) return;
  const float2* base = (const float2*)(logits + (size_t)(b * SS + 1) * VV) + c;
  float a0 = 0, a1 = 0, b0 = 0, b1 = 0, e0 = 0, e1 = 0, f0 = 0, f1 = 0;
  float g0 = 0, g1 = 0, h0 = 0, h1 = 0, i0 = 0, i1 = 0, j0 = 0, j1 = 0;
  #pragma unroll 2
  for (int s = 0; s < 64; ++s) {
    float2 x0 = base[(size_t)(s)       * NF2];
    float2 x1 = base[(size_t)(s +  64) * NF2];
    float2 x2 = base[(size_t)(s + 128) * NF2];
    float2 x3 = base[(size_t)(s + 192) * NF2];
    a0 = fmaf(__expf(x0.x), zi[s      ], a0);  a1 = fmaf(__expf(x0.y), zi[s      ], a1);
    b0 = fmaf(__expf(x1.x), zi[s +  64], b0);  b1 = fmaf(__expf(x1.y), zi[s +  64], b1);
    e0 = fmaf(__expf(x2.x), zi[s + 128], e0);  e1 = fmaf(__expf(x2.y), zi[s + 128], e1);
    f0 = fmaf(__expf(x3.x), zi[s + 192], f0);  f1 = fmaf(__expf(x3.y), zi[s + 192], f1);
    g0 = fmaxf(g0, mm[s      ] != 0.f ? x0.x : 0.f); g1 = fmaxf(g1, mm[s      ] != 0.f ? x0.y : 0.f);
    h0 = fmaxf(h0, mm[s +  64] != 0.f ? x1.x : 0.f); h1 = fmaxf(h1, mm[s +  64] != 0.f ? x1.y : 0.f);
    i0 = fmaxf(i0, mm[s + 128] != 0.f ? x2.x : 0.f); i1 = fmaxf(i1, mm[s + 128] != 0.f ? x2.y : 0.f);
    j0 = fmaxf(j0, mm[s + 192] != 0.f ? x3.x : 0.f); j1 = fmaxf(j1, mm[s + 192] != 0.f ? x3.y : 0.f);
  }
  float sa = (a0 + b0) + (e0 + f0);
  float sb = (a1 + b1) + (e1 + f1);
  float ma = fmaxf(fmaxf(g0, h0), fmaxf(i0, j0));
  float mb = fmaxf(fmaxf(g1, h1), fmaxf(i1, j1));
  size_t o = (size_t)b * VV + 2 * (size_t)c;
  *(float2*)(o_rss + o)   = make_float2(sa, sb);
  *(float2*)(o_rrepr + o) = make_float2(log1pf(ma), log1pf(mb));
}

// ---------------------------------------------------------------------------
// W_tok (P,H) -> Wt (H,P) so the expert GEMM reads W coalesced.
// ---------------------------------------------------------------------------
__global__ __launch_bounds__(256) void transw_kernel(
    const float* __restrict__ W, float* __restrict__ Wt)
{
  int i = blockIdx.x * 256 + threadIdx.x;
  if (i < PP * HH) {
    int p = i / HH, k = i % HH;
    Wt[k * PP + p] = W[i];
  }
}

// ---------------------------------------------------------------------------
// expert_repr[b,s,p] = (hiddens[b,s,:] . W_tok[p,:] + b_tok[p]) * mask[b,s]
// One block per (b,s) row; hidden row staged in LDS; Wt reads coalesced.
// ---------------------------------------------------------------------------
__global__ __launch_bounds__(256) void expertk_kernel(
    const float* __restrict__ hs, const float* __restrict__ amask,
    const float* __restrict__ Wt, const float* __restrict__ btok,
    float* __restrict__ o_er)
{
  const int row = blockIdx.x;
  const int b = row >> 8, s = row & 255;
  const float* hp = hs + (size_t)(b * SS + s + 1) * HH;
  __shared__ float h[HH];
  __shared__ float psum[8][PP];
  for (int i = threadIdx.x; i < HH; i += 256) h[i] = hp[i];
  __syncthreads();
  const int p = threadIdx.x & 31, g = threadIdx.x >> 5;
  float acc = 0.0f;
  #pragma unroll 8
  for (int k = g * 96; k < g * 96 + 96; ++k) acc = fmaf(h[k], Wt[k * PP + p], acc);
  psum[g][p] = acc;
  __syncthreads();
  if (threadIdx.x < PP) {
    float r = 0.0f;
    #pragma unroll
    for (int g2 = 0; g2 < 8; ++g2) r += psum[g2][threadIdx.x];
    float mval = amask[b * SS + s + 1];
    o_er[(size_t)row * PP + threadIdx.x] = (r + btok[threadIdx.x]) * mval;
  }
}

// ---------------------------------------------------------------------------
// avg_cond = sum(rm_seq)/B ; avg_marg = sum_v max_b rm_seq[b,v]
// ---------------------------------------------------------------------------
__global__ __launch_bounds__(256) void reducerm_kernel(
    const float* __restrict__ rm, float* __restrict__ out01)
{
  int v = blockIdx.x * 256 + threadIdx.x;
  float sm = 0.0f, mx = 0.0f;
  if (v < VV) {
    #pragma unroll
    for (int b = 0; b < BB; ++b) {
      float r = rm[(size_t)b * VV + v];
      sm += r; mx = fmaxf(mx, r);
    }
  }
  __shared__ float rs[256], rx[256];
  rs[threadIdx.x] = sm; rx[threadIdx.x] = mx;
  __syncthreads();
  #pragma unroll
  for (int st = 128; st > 0; st >>= 1) {
    if (threadIdx.x < st) {
      rs[threadIdx.x] += rs[threadIdx.x + st];
      rx[threadIdx.x] += rx[threadIdx.x + st];
    }
    __syncthreads();
  }
  if (threadIdx.x == 0) {
    atomicAdd(&out01[0], rs[0] * (1.0f / BB));
    atomicAdd(&out01[1], rx[0]);
  }
}

extern "C" void kernel_launch(void* const* d_in, const int* in_sizes, int n_in,
                              void* d_out, int out_size, void* d_ws, size_t ws_size,
                              hipStream_t stream) {
  const float* hs     = (const float*)d_in[0];  // (16,257,768)
  const float* logits = (const float*)d_in[1];  // (16,257,30522)
  const float* amask  = (const float*)d_in[2];  // (16,257)
  const float* W      = (const float*)d_in[3];  // (32,768)
  const float* btok   = (const float*)d_in[4];  // (32,)
  // d_in[5] = topk scalar (8), compile-time constant here.

  float* out    = (float*)d_out;
  float* o_cond = out;                                  // [0],[1]
  float* o_rm   = out + 2;                              // (16,30522)
  float* o_rss  = o_rm + (size_t)BB * VV;               // (16,30522)
  float* o_mask = o_rss + (size_t)BB * VV;              // (16,256)
  float* o_rrepr= o_mask + (size_t)BB * SP;             // (16,30522)
  float* o_ids  = o_rrepr + (size_t)BB * VV;            // (16,256,8) as float
  float* o_er   = o_ids + (size_t)BB * SP * KK;         // (16,256,32)
  float* o_w    = o_er + (size_t)BB * SP * PP;          // (16,256,8)

  float* wsf  = (float*)d_ws;
  float* invZ = wsf;            // 4096 floats
  float* Wt   = wsf + 4096;     // 24576 floats

  // zero avg_cond, avg_marg, rm_seq (contiguous prefix)
  hipMemsetAsync(out, 0, (2 + (size_t)BB * VV) * sizeof(float), stream);

  rowstats_kernel<<<BB * SP, 256, 0, stream>>>(logits, amask, invZ, o_rm, o_mask, o_ids, o_w);
  colstats_kernel<<<dim3((NF2 + 255) / 256, BB), 256, 0, stream>>>(logits, amask, invZ, o_rss, o_rrepr);
  transw_kernel<<<(PP * HH + 255) / 256, 256, 0, stream>>>(W, Wt);
  expertk_kernel<<<BB * SP, 256, 0, stream>>>(hs, amask, Wt, btok, o_er);
  reducerm_kernel<<<(VV + 255) / 256, 256, 0, stream>>>(o_rm, o_cond);
}